// Round 13
// baseline (212.484 us; speedup 1.0000x reference)
//
#include <hip/hip_runtime.h>
#include <stdint.h>

#define C    14
#define CX   17      // C+3
#define PERC 51
#define HID  256

typedef __attribute__((ext_vector_type(4))) short  bf16x4;
typedef __attribute__((ext_vector_type(8))) short  bf16x8;
typedef __attribute__((ext_vector_type(4))) float  f32x4;
typedef __attribute__((ext_vector_type(8))) unsigned short u16x8;
typedef __attribute__((ext_vector_type(2))) uint32_t u32x2;

// ---------------- bf16 helpers ----------------
__device__ __forceinline__ float bfu(unsigned short u) {
  return __uint_as_float(((uint32_t)u) << 16);
}
__device__ __forceinline__ unsigned short bf16r(float f) {  // RNE (weights prep only)
  uint32_t u = __float_as_uint(f);
  return (unsigned short)((u + 0x7fffu + ((u >> 16) & 1u)) >> 16);
}
// Half-up pack (R8 known-good): round then take high 16 bits of each f32.
__device__ __forceinline__ uint32_t pack2_bf16(float lo, float hi) {
  const uint32_t ul = __float_as_uint(lo) + 0x8000u;
  const uint32_t uh = __float_as_uint(hi) + 0x8000u;
#if __has_builtin(__builtin_amdgcn_perm)
  return __builtin_amdgcn_perm(uh, ul, 0x07060302u);  // {uh[31:16], ul[31:16]}
#else
  return (uh & 0xffff0000u) | (ul >> 16);
#endif
}
__device__ __forceinline__ unsigned short pack1_bf16(float f) {
  return (unsigned short)((__float_as_uint(f) + 0x8000u) >> 16);
}

// ---------------- MFMA wrappers ----------------
__device__ __forceinline__ f32x4 mfma32(bf16x8 a, bf16x8 b, f32x4 c) {
  return __builtin_amdgcn_mfma_f32_16x16x32_bf16(a, b, c, 0, 0, 0);
}
#if __has_builtin(__builtin_amdgcn_mfma_f32_16x16x16bf16_1k)
#define HAVE_MFMA16_BUILTIN 1
#endif
__device__ __forceinline__ f32x4 mfma16(bf16x4 a, bf16x4 b, f32x4 c) {
#ifdef HAVE_MFMA16_BUILTIN
  return __builtin_amdgcn_mfma_f32_16x16x16bf16_1k(a, b, c, 0, 0, 0);
#else
  asm volatile("v_mfma_f32_16x16x16_bf16 %0, %1, %2, %0" : "+v"(c) : "v"(a), "v"(b));
  return c;
#endif
}

// ---------------- threefry2x32 (JAX partitionable) ----------------
__device__ __forceinline__ void tf_round(uint32_t& x0, uint32_t& x1, int r) {
  x0 += x1; x1 = (x1 << r) | (x1 >> (32 - r)); x1 ^= x0;
}
__device__ __forceinline__ void threefry2x32(uint32_t k0, uint32_t k1,
                                             uint32_t& x0, uint32_t& x1) {
  const uint32_t ks2 = k0 ^ k1 ^ 0x1BD11BDAu;
  x0 += k0; x1 += k1;
  tf_round(x0,x1,13); tf_round(x0,x1,15); tf_round(x0,x1,26); tf_round(x0,x1,6);
  x0 += k1; x1 += ks2 + 1u;
  tf_round(x0,x1,17); tf_round(x0,x1,29); tf_round(x0,x1,16); tf_round(x0,x1,24);
  x0 += ks2; x1 += k0 + 2u;
  tf_round(x0,x1,13); tf_round(x0,x1,15); tf_round(x0,x1,26); tf_round(x0,x1,6);
  x0 += k0; x1 += k1 + 3u;
  tf_round(x0,x1,17); tf_round(x0,x1,29); tf_round(x0,x1,16); tf_round(x0,x1,24);
  x0 += k1; x1 += ks2 + 4u;
  tf_round(x0,x1,13); tf_round(x0,x1,15); tf_round(x0,x1,26); tf_round(x0,x1,6);
  x0 += ks2; x1 += k0 + 5u;
}
__device__ __forceinline__ float upd_val(uint32_t gpix) {
  uint32_t fk0 = 0u, fk1 = 1234u;
  threefry2x32(0u, 0u, fk0, fk1);
  uint32_t a = 0u, b = gpix;
  threefry2x32(fk0, fk1, a, b);
  const uint32_t bits = a ^ b;
  const float u = __uint_as_float((bits >> 9) | 0x3f800000u) - 1.0f;
  return (u <= 0.5f) ? 1.0f : 0.0f;
}

// ---------------- kernel 0: weight fragment prep ----------------
// w1f: A-frags of W1^T for mfma_16x16x32: [mt 0..15][k2 0..1][lane][8]
//   k = k2*32 + (l>>4)*8 + j; k==51 carries b1; k>51 -> 0 (lg3/k2=1 relies on this)
// w2f: A-frags of W2^T for mfma_16x16x16: [ks 0..15][lane][4]
__global__ void nca_prep(const float* __restrict__ W1, const float* __restrict__ b1,
                         const float* __restrict__ W2, const float* __restrict__ b2,
                         unsigned short* __restrict__ w1fu,
                         unsigned short* __restrict__ w2fu,
                         float* __restrict__ b2p) {
  const int bid = blockIdx.x, t = threadIdx.x;
  if (bid < 64) {
    const int f = bid * 256 + t;                 // 0..16383
    const int j = f & 7, l = (f >> 3) & 63, k2 = (f >> 9) & 1, mt = f >> 10;
    const int n = mt * 16 + (l & 15);
    const int k = k2 * 32 + ((l >> 4) & 3) * 8 + j;
    float v = 0.0f;
    if (k < PERC)       v = W1[k * HID + n];
    else if (k == PERC) v = b1[n];               // bias row
    w1fu[f] = bf16r(v);
  } else if (bid < 80) {
    const int f = (bid - 64) * 256 + t;          // 0..4095
    const int j = f & 3, l = (f >> 2) & 63, ks = f >> 8;
    const int co = l & 15;
    const int k = ks * 16 + ((l >> 4) & 3) * 4 + j;
    const float v = (co < C) ? W2[k * C + co] : 0.0f;
    w2fu[f] = bf16r(v);
  } else if (t < 16) {
    b2p[t] = (t < C) ? b2[t] : 0.0f;
  }
}

// ---------------- kernel 1: fused NCA step (16x16 pixel tile) ----------------
// Ps layout: pixel stride 60 bf16 (120 B), 7 granules x 16 B (k=0..55).
// 120B stride -> start banks (30p+4g)%32 distinct-even across lanes: adjacent
// windows overlap 2-way = free (no XOR swizzle needed). Granule 7 (k=56..63)
// is all-zero in A (prep) so B reads redirect lg==3 to granule 6 (finite).
// LDS total 32128 B -> 5 blocks/CU.
__global__ __launch_bounds__(256, 5)
void nca_main(const float* __restrict__ x, const float* __restrict__ img,
              const unsigned short* __restrict__ w1fu,
              const unsigned short* __restrict__ w2fu,
              const float* __restrict__ b2p,
              float* __restrict__ out, uint8_t* __restrict__ bplane) {
  __shared__ union {
    unsigned short xcs[18 * 18 * 24];  // bf16 halo tile (31104 B)
    unsigned short Ps[256 * 60];       // perception, stride-60 (30720 B)
  } sh;
  __shared__ float updf[256];

  const int t    = threadIdx.x;
  const int bid  = blockIdx.x;
  const int bb   = bid >> 8;
  const int tile = bid & 255;
  const int row0 = (tile >> 4) << 4, col0 = (tile & 15) << 4;

  // ---- stage xc halo (bf16, zero-padded borders) ----
  for (int e = t; e < 324; e += 256) {
    const int r = e / 18, c = e - r * 18;
    const int gr = row0 + r - 1, gc = col0 + c - 1;
    uint32_t w[8]; unsigned short w16;
    if ((unsigned)gr < 256u && (unsigned)gc < 256u) {
      const size_t gp = (size_t)bb * 65536 + (size_t)gr * 256 + gc;
      const float* xp = x + gp * C;
      float v[17];
      #pragma unroll
      for (int k = 0; k < 7; ++k) {
        const float2 f2 = *(const float2*)(xp + 2 * k);
        v[2 * k] = f2.x; v[2 * k + 1] = f2.y;
      }
      const float* ip = img + ((size_t)gr * 256 + gc) * 3;
      v[14] = ip[0]; v[15] = ip[1]; v[16] = ip[2];
      #pragma unroll
      for (int k = 0; k < 8; ++k)
        w[k] = pack2_bf16(v[2 * k], v[2 * k + 1]);
      w16 = pack1_bf16(v[16]);
    } else {
      #pragma unroll
      for (int k = 0; k < 8; ++k) w[k] = 0u;
      w16 = 0;
    }
    uint32_t* d = (uint32_t*)&sh.xcs[e * 24];
    #pragma unroll
    for (int k = 0; k < 8; ++k) d[k] = w[k];
    sh.xcs[e * 24 + 16] = w16;
  }

  // ---- stochastic update mask (one pixel per thread) ----
  {
    const uint32_t g = ((uint32_t)bb * 256u + (uint32_t)(row0 + (t >> 4))) * 256u
                       + (uint32_t)(col0 + (t & 15));
    updf[t] = upd_val(g);
  }
  __syncthreads();   // B1: xcs halo visible to all waves

  // ---- perception (pixel t) into registers ----
  const int pr = t >> 4, pc = t & 15;
  float pe[56];
  #pragma unroll
  for (int h = 0; h < 2; ++h) {
    u16x8 nb[9];
    #pragma unroll
    for (int i = 0; i < 3; ++i)
      #pragma unroll
      for (int j = 0; j < 3; ++j)
        nb[i * 3 + j] = *(const u16x8*)&sh.xcs[((pr + i) * 18 + (pc + j)) * 24 + h * 8];
    #pragma unroll
    for (int cc = 0; cc < 8; ++cc) {
      const int ch = h * 8 + cc;
      const float a00 = bfu(nb[0][cc]), a01 = bfu(nb[1][cc]), a02 = bfu(nb[2][cc]);
      const float a10 = bfu(nb[3][cc]), a11 = bfu(nb[4][cc]), a12 = bfu(nb[5][cc]);
      const float a20 = bfu(nb[6][cc]), a21 = bfu(nb[7][cc]), a22 = bfu(nb[8][cc]);
      pe[3 * ch + 0] = a11;
      pe[3 * ch + 1] = ((a02 - a00) + 2.0f * (a12 - a10) + (a22 - a20)) * 0.125f;
      pe[3 * ch + 2] = ((a20 - a00) + 2.0f * (a21 - a01) + (a22 - a02)) * 0.125f;
    }
  }
  {
    float a[9];
    #pragma unroll
    for (int i = 0; i < 3; ++i)
      #pragma unroll
      for (int j = 0; j < 3; ++j)
        a[i * 3 + j] = bfu(sh.xcs[((pr + i) * 18 + (pc + j)) * 24 + 16]);
    pe[48] = a[4];
    pe[49] = ((a[2] - a[0]) + 2.0f * (a[5] - a[3]) + (a[8] - a[6])) * 0.125f;
    pe[50] = ((a[6] - a[0]) + 2.0f * (a[7] - a[1]) + (a[8] - a[2])) * 0.125f;
  }
  pe[51] = 1.0f;                       // bias row (k=51 of W1 frags = b1)
  #pragma unroll
  for (int k = 52; k < 56; ++k) pe[k] = 0.0f;

  __syncthreads();   // B2: all xcs reads done before Ps overwrites union

  // ---- pack bf16, store to Ps (stride 60, 7 granules) ----
  #pragma unroll
  for (int g = 0; g < 7; ++g) {
    uint4 v;
    v.x = pack2_bf16(pe[g * 8 + 0], pe[g * 8 + 1]);
    v.y = pack2_bf16(pe[g * 8 + 2], pe[g * 8 + 3]);
    v.z = pack2_bf16(pe[g * 8 + 4], pe[g * 8 + 5]);
    v.w = pack2_bf16(pe[g * 8 + 6], pe[g * 8 + 7]);
    *(uint4*)&sh.Ps[t * 60 + g * 8] = v;
  }
  __syncthreads();   // B3: Ps cross-thread handoff (R4 lesson)

  // ---- GEMMs: wave w owns pixels w*64..w*64+63 ----
  const int lane = t & 63;
  const int wv   = t >> 6;
  const int wbase = wv << 6;
  const int lg = lane >> 4;    // lane group (k-group / row-group)
  const int lc = lane & 15;    // pixel-within-16 (MFMA col)

  // B-fragments: nc-invariant — load ONCE. lg==3's k2=1 slice (k=56..63) has
  // all-zero A weights; read granule 6 instead (finite values, product = 0).
  const int g1 = (lg < 3) ? (4 + lg) : 6;
  bf16x8 bF0[4], bF1[4];
  #pragma unroll
  for (int nt = 0; nt < 4; ++nt) {
    const int pix = wbase + nt * 16 + lc;
    bF0[nt] = *(const bf16x8*)&sh.Ps[pix * 60 + lg * 8];
    bF1[nt] = *(const bf16x8*)&sh.Ps[pix * 60 + g1 * 8];
  }

  f32x4 dxacc[4];
  {
    const float4 b2v = *(const float4*)(b2p + lg * 4);
    #pragma unroll
    for (int nt = 0; nt < 4; ++nt)
      dxacc[nt] = (f32x4){b2v.x, b2v.y, b2v.z, b2v.w};
  }

  #pragma unroll
  for (int nc = 0; nc < 4; ++nc) {          // hidden 64-chunk
    bf16x8 aFc[4][2];
    #pragma unroll
    for (int m4 = 0; m4 < 4; ++m4)
      #pragma unroll
      for (int k2 = 0; k2 < 2; ++k2)
        aFc[m4][k2] = *(const bf16x8*)(w1fu + (((((nc * 4 + m4) * 2 + k2) * 64) + lane) << 3));

    f32x4 acc[4][4];
    #pragma unroll
    for (int m4 = 0; m4 < 4; ++m4)
      #pragma unroll
      for (int nt = 0; nt < 4; ++nt)
        acc[m4][nt] = (f32x4){0.0f, 0.0f, 0.0f, 0.0f};   // b1 folded into k=51

    #pragma unroll
    for (int nt = 0; nt < 4; ++nt) {
      #pragma unroll
      for (int m4 = 0; m4 < 4; ++m4) acc[m4][nt] = mfma32(aFc[m4][0], bF0[nt], acc[m4][nt]);
      #pragma unroll
      for (int m4 = 0; m4 < 4; ++m4) acc[m4][nt] = mfma32(aFc[m4][1], bF1[nt], acc[m4][nt]);
    }

    // GEMM2 partial: relu + half-up pack feeds the K=16 MFMA directly
    #pragma unroll
    for (int m4 = 0; m4 < 4; ++m4) {
      const bf16x4 wf = *(const bf16x4*)(w2fu + ((((nc * 4 + m4) * 64) + lane) << 2));
      #pragma unroll
      for (int nt = 0; nt < 4; ++nt) {
        u32x2 pw;
        pw.x = pack2_bf16(fmaxf(acc[m4][nt][0], 0.0f), fmaxf(acc[m4][nt][1], 0.0f));
        pw.y = pack2_bf16(fmaxf(acc[m4][nt][2], 0.0f), fmaxf(acc[m4][nt][3], 0.0f));
        dxacc[nt] = mfma16(wf, __builtin_bit_cast(bf16x4, pw), dxacc[nt]);
      }
    }
  }
#ifndef HAVE_MFMA16_BUILTIN
  asm volatile("s_nop 7\n\ts_nop 7" :::);
#endif

  // ---- epilogue: x_new = x + 0.1 * dx * upd  (+ TILED alive-bit plane) ----
  #pragma unroll
  for (int nt = 0; nt < 4; ++nt) {
    const int pix = wbase + nt * 16 + lc;
    const float sc = 0.1f * updf[pix];
    const int gr = row0 + (pix >> 4), gc = col0 + (pix & 15);
    const size_t gp = (size_t)bb * 65536 + (size_t)gr * 256 + gc;
    const float* xp = x + gp * C + lg * 4;
    float* op = out + gp * C + lg * 4;
    const f32x4 d = dxacc[nt];
    if (lg < 3) {
      const float2 u0 = *(const float2*)xp;
      const float2 u1 = *(const float2*)(xp + 2);
      const float r0 = u0.x + d[0] * sc, r1 = u0.y + d[1] * sc;
      const float r2 = u1.x + d[2] * sc, r3 = u1.y + d[3] * sc;
      *(float2*)op = make_float2(r0, r1);
      *(float2*)(op + 2) = make_float2(r2, r3);
      if (lg == 0) {
        // exact alive bits: bit0 = old ch0 > 0.1 (f32), bit1 = new ch0 > 0.1
        bplane[(size_t)bb * 65536 + (size_t)tile * 256 + pix] =
            (uint8_t)((u0.x > 0.1f ? 1 : 0) | (r0 > 0.1f ? 2 : 0));
      }
    } else {
      const float2 u0 = *(const float2*)xp;
      *(float2*)op = make_float2(u0.x + d[0] * sc, u0.y + d[1] * sc);
    }
  }
}

// ---------------- kernel 2: alive masking via tiled bit-plane ---------------
__global__ __launch_bounds__(256)
void nca_mask(const uint8_t* __restrict__ bp, float* __restrict__ out) {
  __shared__ uint8_t sb[18 * 18];
  const int t    = threadIdx.x;
  const int bid  = blockIdx.x;
  const int bb   = bid >> 8;
  const int tile = bid & 255;
  const int row0 = (tile >> 4) << 4, col0 = (tile & 15) << 4;

  for (int e = t; e < 324; e += 256) {
    const int r = e / 18, c = e - r * 18;
    const int gr = row0 + r - 1, gc = col0 + c - 1;
    uint8_t v = 0;   // border: pooled NEG_INF -> both tests false -> bits 0
    if ((unsigned)gr < 256u && (unsigned)gc < 256u) {
      const int tr = gr >> 4, tc = gc >> 4;          // tiled layout lookup
      v = bp[(size_t)bb * 65536 + (size_t)((tr << 4) + tc) * 256
             + ((gr & 15) << 4) + (gc & 15)];
    }
    sb[e] = v;
  }
  __syncthreads();

  const int pr = t >> 4, pc = t & 15;
  int m = 0;
  #pragma unroll
  for (int i = 0; i < 3; ++i)
    #pragma unroll
    for (int j = 0; j < 3; ++j)
      m |= sb[(pr + i) * 18 + pc + j];
  // alive = (pooled old > 0.1) && (pooled new > 0.1) = bit0 & bit1 of the OR
  if ((m & 3) != 3) {
    const size_t gp = ((size_t)bb * 256 + row0 + pr) * 256 + col0 + pc;
    float* __restrict__ o = out + gp * C;
    const float2 z = make_float2(0.0f, 0.0f);
    #pragma unroll
    for (int k = 0; k < 7; ++k) ((float2*)o)[k] = z;
  }
}

// ---------------- launch ----------------
extern "C" void kernel_launch(void* const* d_in, const int* in_sizes, int n_in,
                              void* d_out, int out_size, void* d_ws, size_t ws_size,
                              hipStream_t stream) {
  const float* x  = (const float*)d_in[0];
  const float* im = (const float*)d_in[1];
  const float* W1 = (const float*)d_in[2];
  const float* b1 = (const float*)d_in[3];
  const float* W2 = (const float*)d_in[4];
  const float* b2 = (const float*)d_in[5];
  float* out   = (float*)d_out;
  uint8_t* bplane = (uint8_t*)d_ws;                              // 1 MiB (tiled)
  unsigned short* w1fu = (unsigned short*)((char*)d_ws + 1048576);        // 32 KiB
  unsigned short* w2fu = (unsigned short*)((char*)d_ws + 1048576 + 32768); // 8 KiB
  float* b2p = (float*)((char*)d_ws + 1048576 + 32768 + 8192);   // 64 B

  nca_prep<<<81,   256, 0, stream>>>(W1, b1, W2, b2, w1fu, w2fu, b2p);
  nca_main<<<4096, 256, 0, stream>>>(x, im, w1fu, w2fu, b2p, out, bplane);
  nca_mask<<<4096, 256, 0, stream>>>(bplane, out);
}

// Round 14
// 152.429 us; speedup vs baseline: 1.3940x; 1.3940x over previous
//
#include <hip/hip_runtime.h>
#include <stdint.h>

#define C    14
#define CX   17      // C+3
#define PERC 51
#define HID  256

typedef __attribute__((ext_vector_type(4))) short  bf16x4;
typedef __attribute__((ext_vector_type(8))) short  bf16x8;
typedef __attribute__((ext_vector_type(4))) float  f32x4;
typedef __attribute__((ext_vector_type(8))) unsigned short u16x8;
typedef __attribute__((ext_vector_type(2))) uint32_t u32x2;

// ---------------- bf16 helpers ----------------
__device__ __forceinline__ float bfu(unsigned short u) {
  return __uint_as_float(((uint32_t)u) << 16);
}
__device__ __forceinline__ unsigned short bf16r(float f) {  // RNE (weights prep only)
  uint32_t u = __float_as_uint(f);
  return (unsigned short)((u + 0x7fffu + ((u >> 16) & 1u)) >> 16);
}
// Half-up pack (R8 known-good): round then take high 16 bits of each f32.
__device__ __forceinline__ uint32_t pack2_bf16(float lo, float hi) {
  const uint32_t ul = __float_as_uint(lo) + 0x8000u;
  const uint32_t uh = __float_as_uint(hi) + 0x8000u;
#if __has_builtin(__builtin_amdgcn_perm)
  return __builtin_amdgcn_perm(uh, ul, 0x07060302u);  // {uh[31:16], ul[31:16]}
#else
  return (uh & 0xffff0000u) | (ul >> 16);
#endif
}
__device__ __forceinline__ unsigned short pack1_bf16(float f) {
  return (unsigned short)((__float_as_uint(f) + 0x8000u) >> 16);
}

// ---------------- MFMA wrappers ----------------
__device__ __forceinline__ f32x4 mfma32(bf16x8 a, bf16x8 b, f32x4 c) {
  return __builtin_amdgcn_mfma_f32_16x16x32_bf16(a, b, c, 0, 0, 0);
}
#if __has_builtin(__builtin_amdgcn_mfma_f32_16x16x16bf16_1k)
#define HAVE_MFMA16_BUILTIN 1
#endif
__device__ __forceinline__ f32x4 mfma16(bf16x4 a, bf16x4 b, f32x4 c) {
#ifdef HAVE_MFMA16_BUILTIN
  return __builtin_amdgcn_mfma_f32_16x16x16bf16_1k(a, b, c, 0, 0, 0);
#else
  asm volatile("v_mfma_f32_16x16x16_bf16 %0, %1, %2, %0" : "+v"(c) : "v"(a), "v"(b));
  return c;
#endif
}

// ---------------- threefry2x32 (JAX partitionable) ----------------
__device__ __forceinline__ void tf_round(uint32_t& x0, uint32_t& x1, int r) {
  x0 += x1; x1 = (x1 << r) | (x1 >> (32 - r)); x1 ^= x0;
}
__device__ __forceinline__ void threefry2x32(uint32_t k0, uint32_t k1,
                                             uint32_t& x0, uint32_t& x1) {
  const uint32_t ks2 = k0 ^ k1 ^ 0x1BD11BDAu;
  x0 += k0; x1 += k1;
  tf_round(x0,x1,13); tf_round(x0,x1,15); tf_round(x0,x1,26); tf_round(x0,x1,6);
  x0 += k1; x1 += ks2 + 1u;
  tf_round(x0,x1,17); tf_round(x0,x1,29); tf_round(x0,x1,16); tf_round(x0,x1,24);
  x0 += ks2; x1 += k0 + 2u;
  tf_round(x0,x1,13); tf_round(x0,x1,15); tf_round(x0,x1,26); tf_round(x0,x1,6);
  x0 += k0; x1 += k1 + 3u;
  tf_round(x0,x1,17); tf_round(x0,x1,29); tf_round(x0,x1,16); tf_round(x0,x1,24);
  x0 += k1; x1 += ks2 + 4u;
  tf_round(x0,x1,13); tf_round(x0,x1,15); tf_round(x0,x1,26); tf_round(x0,x1,6);
  x0 += ks2; x1 += k0 + 5u;
}
__device__ __forceinline__ float upd_val(uint32_t gpix) {
  uint32_t fk0 = 0u, fk1 = 1234u;
  threefry2x32(0u, 0u, fk0, fk1);
  uint32_t a = 0u, b = gpix;
  threefry2x32(fk0, fk1, a, b);
  const uint32_t bits = a ^ b;
  const float u = __uint_as_float((bits >> 9) | 0x3f800000u) - 1.0f;
  return (u <= 0.5f) ? 1.0f : 0.0f;
}

// ---------------- kernel 0: weight fragment prep ----------------
__global__ void nca_prep(const float* __restrict__ W1, const float* __restrict__ b1,
                         const float* __restrict__ W2, const float* __restrict__ b2,
                         unsigned short* __restrict__ w1fu,
                         unsigned short* __restrict__ w2fu,
                         float* __restrict__ b2p) {
  const int bid = blockIdx.x, t = threadIdx.x;
  if (bid < 64) {
    const int f = bid * 256 + t;                 // 0..16383
    const int j = f & 7, l = (f >> 3) & 63, k2 = (f >> 9) & 1, mt = f >> 10;
    const int n = mt * 16 + (l & 15);
    const int k = k2 * 32 + ((l >> 4) & 3) * 8 + j;
    float v = 0.0f;
    if (k < PERC)       v = W1[k * HID + n];
    else if (k == PERC) v = b1[n];               // bias row
    w1fu[f] = bf16r(v);
  } else if (bid < 80) {
    const int f = (bid - 64) * 256 + t;          // 0..4095
    const int j = f & 3, l = (f >> 2) & 63, ks = f >> 8;
    const int co = l & 15;
    const int k = ks * 16 + ((l >> 4) & 3) * 4 + j;
    const float v = (co < C) ? W2[k * C + co] : 0.0f;
    w2fu[f] = bf16r(v);
  } else if (t < 16) {
    b2p[t] = (t < C) ? b2[t] : 0.0f;
  }
}

// ---------------- kernel 1: fused NCA step (16x16 pixel tile) ----------------
__global__ __launch_bounds__(256, 4)
void nca_main(const float* __restrict__ x, const float* __restrict__ img,
              const unsigned short* __restrict__ w1fu,
              const unsigned short* __restrict__ w2fu,
              const float* __restrict__ b2p,
              float* __restrict__ out, uint8_t* __restrict__ bplane) {
  // xcs and Ps have disjoint lifetimes separated by a barrier -> union
  // (33.8 KB LDS, 4 blocks/CU).
  __shared__ union {
    unsigned short xcs[18 * 18 * 24];  // bf16 halo tile, ch padded to 24 (31104 B)
    unsigned short Ps[256 * 64];       // perception, XOR-swizzled (32768 B)
  } sh;
  __shared__ float updf[256];

  const int t    = threadIdx.x;
  const int bid  = blockIdx.x;
  const int bb   = bid >> 8;
  const int tile = bid & 255;
  const int row0 = (tile >> 4) << 4, col0 = (tile & 15) << 4;

  // ---- stage xc halo (bf16, zero-padded borders) ----
  for (int e = t; e < 324; e += 256) {
    const int r = e / 18, c = e - r * 18;
    const int gr = row0 + r - 1, gc = col0 + c - 1;
    uint32_t w[8]; unsigned short w16;
    if ((unsigned)gr < 256u && (unsigned)gc < 256u) {
      const size_t gp = (size_t)bb * 65536 + (size_t)gr * 256 + gc;
      const float* xp = x + gp * C;
      float v[17];
      #pragma unroll
      for (int k = 0; k < 7; ++k) {
        const float2 f2 = *(const float2*)(xp + 2 * k);
        v[2 * k] = f2.x; v[2 * k + 1] = f2.y;
      }
      const float* ip = img + ((size_t)gr * 256 + gc) * 3;
      v[14] = ip[0]; v[15] = ip[1]; v[16] = ip[2];
      #pragma unroll
      for (int k = 0; k < 8; ++k)
        w[k] = pack2_bf16(v[2 * k], v[2 * k + 1]);
      w16 = pack1_bf16(v[16]);
    } else {
      #pragma unroll
      for (int k = 0; k < 8; ++k) w[k] = 0u;
      w16 = 0;
    }
    uint32_t* d = (uint32_t*)&sh.xcs[e * 24];
    #pragma unroll
    for (int k = 0; k < 8; ++k) d[k] = w[k];
    sh.xcs[e * 24 + 16] = w16;
  }

  // ---- stochastic update mask (one pixel per thread) ----
  {
    const uint32_t g = ((uint32_t)bb * 256u + (uint32_t)(row0 + (t >> 4))) * 256u
                       + (uint32_t)(col0 + (t & 15));
    updf[t] = upd_val(g);
  }
  __syncthreads();   // B1: xcs halo visible to all waves

  // ---- perception (pixel t) into registers ----
  const int pr = t >> 4, pc = t & 15;
  float pe[64];
  #pragma unroll
  for (int h = 0; h < 2; ++h) {
    u16x8 nb[9];
    #pragma unroll
    for (int i = 0; i < 3; ++i)
      #pragma unroll
      for (int j = 0; j < 3; ++j)
        nb[i * 3 + j] = *(const u16x8*)&sh.xcs[((pr + i) * 18 + (pc + j)) * 24 + h * 8];
    #pragma unroll
    for (int cc = 0; cc < 8; ++cc) {
      const int ch = h * 8 + cc;
      const float a00 = bfu(nb[0][cc]), a01 = bfu(nb[1][cc]), a02 = bfu(nb[2][cc]);
      const float a10 = bfu(nb[3][cc]), a11 = bfu(nb[4][cc]), a12 = bfu(nb[5][cc]);
      const float a20 = bfu(nb[6][cc]), a21 = bfu(nb[7][cc]), a22 = bfu(nb[8][cc]);
      pe[3 * ch + 0] = a11;
      pe[3 * ch + 1] = ((a02 - a00) + 2.0f * (a12 - a10) + (a22 - a20)) * 0.125f;
      pe[3 * ch + 2] = ((a20 - a00) + 2.0f * (a21 - a01) + (a22 - a02)) * 0.125f;
    }
  }
  {
    float a[9];
    #pragma unroll
    for (int i = 0; i < 3; ++i)
      #pragma unroll
      for (int j = 0; j < 3; ++j)
        a[i * 3 + j] = bfu(sh.xcs[((pr + i) * 18 + (pc + j)) * 24 + 16]);
    pe[48] = a[4];
    pe[49] = ((a[2] - a[0]) + 2.0f * (a[5] - a[3]) + (a[8] - a[6])) * 0.125f;
    pe[50] = ((a[6] - a[0]) + 2.0f * (a[7] - a[1]) + (a[8] - a[2])) * 0.125f;
  }
  pe[51] = 1.0f;                       // bias row (k=51 of W1 frags = b1)
  #pragma unroll
  for (int k = 52; k < 64; ++k) pe[k] = 0.0f;

  __syncthreads();   // B2: all xcs reads done before Ps overwrites union

  // ---- pack bf16, store swizzled to Ps ----
  #pragma unroll
  for (int g = 0; g < 8; ++g) {
    uint4 v;
    v.x = pack2_bf16(pe[g * 8 + 0], pe[g * 8 + 1]);
    v.y = pack2_bf16(pe[g * 8 + 2], pe[g * 8 + 3]);
    v.z = pack2_bf16(pe[g * 8 + 4], pe[g * 8 + 5]);
    v.w = pack2_bf16(pe[g * 8 + 6], pe[g * 8 + 7]);
    *(uint4*)&sh.Ps[(t << 6) + ((g ^ (t & 7)) << 3)] = v;
  }

  const int lane = t & 63;
  const int wv   = t >> 6;
  const int wbase = wv << 6;
  const int lg = lane >> 4;    // lane group (k-group / row-group)
  const int lc = lane & 15;    // pixel-within-16 (MFMA col)

  // Preload nc=0 A-fragments BEFORE the barrier (latency hides under the wait).
  bf16x8 aFc[4][2];
  #pragma unroll
  for (int m4 = 0; m4 < 4; ++m4)
    #pragma unroll
    for (int k2 = 0; k2 < 2; ++k2)
      aFc[m4][k2] = *(const bf16x8*)(w1fu + ((((m4 * 2 + k2) * 64) + lane) << 3));

  __syncthreads();   // B3: Ps cross-thread handoff (R4 lesson)

  // B-fragments: nc-invariant — load ONCE.
  bf16x8 bF0[4], bF1[4];
  #pragma unroll
  for (int nt = 0; nt < 4; ++nt) {
    const int pix = wbase + nt * 16 + lc;
    bF0[nt] = *(const bf16x8*)&sh.Ps[(pix << 6) + ((lg ^ (pix & 7)) << 3)];
    bF1[nt] = *(const bf16x8*)&sh.Ps[(pix << 6) + (((4 + lg) ^ (pix & 7)) << 3)];
  }

  // Dual GEMM2 accumulator chains (halve the mfma16 dependency depth):
  // even m4 -> dxa (b2 init), odd m4 -> dxb (zero init); final dx = dxa + dxb.
  f32x4 dxa[4], dxb[4];
  {
    const float4 b2v = *(const float4*)(b2p + lg * 4);
    #pragma unroll
    for (int nt = 0; nt < 4; ++nt) {
      dxa[nt] = (f32x4){b2v.x, b2v.y, b2v.z, b2v.w};
      dxb[nt] = (f32x4){0.0f, 0.0f, 0.0f, 0.0f};
    }
  }

  __builtin_amdgcn_s_setprio(1);
  #pragma unroll
  for (int nc = 0; nc < 4; ++nc) {          // hidden 64-chunk
    if (nc > 0) {
      #pragma unroll
      for (int m4 = 0; m4 < 4; ++m4)
        #pragma unroll
        for (int k2 = 0; k2 < 2; ++k2)
          aFc[m4][k2] = *(const bf16x8*)(w1fu + (((((nc * 4 + m4) * 2 + k2) * 64) + lane) << 3));
    }

    f32x4 acc[4][4];
    #pragma unroll
    for (int m4 = 0; m4 < 4; ++m4)
      #pragma unroll
      for (int nt = 0; nt < 4; ++nt)
        acc[m4][nt] = (f32x4){0.0f, 0.0f, 0.0f, 0.0f};   // b1 folded into k=51

    #pragma unroll
    for (int nt = 0; nt < 4; ++nt) {
      #pragma unroll
      for (int m4 = 0; m4 < 4; ++m4) acc[m4][nt] = mfma32(aFc[m4][0], bF0[nt], acc[m4][nt]);
      #pragma unroll
      for (int m4 = 0; m4 < 4; ++m4) acc[m4][nt] = mfma32(aFc[m4][1], bF1[nt], acc[m4][nt]);
    }

    // GEMM2 partial: relu + half-up pack feeds the K=16 MFMA directly
    #pragma unroll
    for (int m4 = 0; m4 < 4; ++m4) {
      const bf16x4 wf = *(const bf16x4*)(w2fu + ((((nc * 4 + m4) * 64) + lane) << 2));
      #pragma unroll
      for (int nt = 0; nt < 4; ++nt) {
        u32x2 pw;
        pw.x = pack2_bf16(fmaxf(acc[m4][nt][0], 0.0f), fmaxf(acc[m4][nt][1], 0.0f));
        pw.y = pack2_bf16(fmaxf(acc[m4][nt][2], 0.0f), fmaxf(acc[m4][nt][3], 0.0f));
        if (m4 & 1) dxb[nt] = mfma16(wf, __builtin_bit_cast(bf16x4, pw), dxb[nt]);
        else        dxa[nt] = mfma16(wf, __builtin_bit_cast(bf16x4, pw), dxa[nt]);
      }
    }
  }
  __builtin_amdgcn_s_setprio(0);
#ifndef HAVE_MFMA16_BUILTIN
  asm volatile("s_nop 7\n\ts_nop 7" :::);
#endif

  // ---- epilogue: x_new = x + 0.1 * dx * upd  (+ TILED alive-bit plane) ----
  #pragma unroll
  for (int nt = 0; nt < 4; ++nt) {
    const int pix = wbase + nt * 16 + lc;
    const float sc = 0.1f * updf[pix];
    const int gr = row0 + (pix >> 4), gc = col0 + (pix & 15);
    const size_t gp = (size_t)bb * 65536 + (size_t)gr * 256 + gc;
    const float* xp = x + gp * C + lg * 4;
    float* op = out + gp * C + lg * 4;
    const f32x4 d = dxa[nt] + dxb[nt];
    if (lg < 3) {
      const float2 u0 = *(const float2*)xp;
      const float2 u1 = *(const float2*)(xp + 2);
      const float r0 = u0.x + d[0] * sc, r1 = u0.y + d[1] * sc;
      const float r2 = u1.x + d[2] * sc, r3 = u1.y + d[3] * sc;
      *(float2*)op = make_float2(r0, r1);
      *(float2*)(op + 2) = make_float2(r2, r3);
      if (lg == 0) {
        // exact alive bits: bit0 = old ch0 > 0.1 (f32), bit1 = new ch0 > 0.1
        bplane[(size_t)bb * 65536 + (size_t)tile * 256 + pix] =
            (uint8_t)((u0.x > 0.1f ? 1 : 0) | (r0 > 0.1f ? 2 : 0));
      }
    } else {
      const float2 u0 = *(const float2*)xp;
      *(float2*)op = make_float2(u0.x + d[0] * sc, u0.y + d[1] * sc);
    }
  }
}

// ---------------- kernel 2: alive masking via tiled bit-plane ---------------
__global__ __launch_bounds__(256)
void nca_mask(const uint8_t* __restrict__ bp, float* __restrict__ out) {
  __shared__ uint8_t sb[18 * 18];
  const int t    = threadIdx.x;
  const int bid  = blockIdx.x;
  const int bb   = bid >> 8;
  const int tile = bid & 255;
  const int row0 = (tile >> 4) << 4, col0 = (tile & 15) << 4;

  for (int e = t; e < 324; e += 256) {
    const int r = e / 18, c = e - r * 18;
    const int gr = row0 + r - 1, gc = col0 + c - 1;
    uint8_t v = 0;   // border: pooled NEG_INF -> both tests false -> bits 0
    if ((unsigned)gr < 256u && (unsigned)gc < 256u) {
      const int tr = gr >> 4, tc = gc >> 4;          // tiled layout lookup
      v = bp[(size_t)bb * 65536 + (size_t)((tr << 4) + tc) * 256
             + ((gr & 15) << 4) + (gc & 15)];
    }
    sb[e] = v;
  }
  __syncthreads();

  const int pr = t >> 4, pc = t & 15;
  int m = 0;
  #pragma unroll
  for (int i = 0; i < 3; ++i)
    #pragma unroll
    for (int j = 0; j < 3; ++j)
      m |= sb[(pr + i) * 18 + pc + j];
  // alive = (pooled old > 0.1) && (pooled new > 0.1) = bit0 & bit1 of the OR
  if ((m & 3) != 3) {
    const size_t gp = ((size_t)bb * 256 + row0 + pr) * 256 + col0 + pc;
    float* __restrict__ o = out + gp * C;
    const float2 z = make_float2(0.0f, 0.0f);
    #pragma unroll
    for (int k = 0; k < 7; ++k) ((float2*)o)[k] = z;
  }
}

// ---------------- launch ----------------
extern "C" void kernel_launch(void* const* d_in, const int* in_sizes, int n_in,
                              void* d_out, int out_size, void* d_ws, size_t ws_size,
                              hipStream_t stream) {
  const float* x  = (const float*)d_in[0];
  const float* im = (const float*)d_in[1];
  const float* W1 = (const float*)d_in[2];
  const float* b1 = (const float*)d_in[3];
  const float* W2 = (const float*)d_in[4];
  const float* b2 = (const float*)d_in[5];
  float* out   = (float*)d_out;
  uint8_t* bplane = (uint8_t*)d_ws;                              // 1 MiB (tiled)
  unsigned short* w1fu = (unsigned short*)((char*)d_ws + 1048576);        // 32 KiB
  unsigned short* w2fu = (unsigned short*)((char*)d_ws + 1048576 + 32768); // 8 KiB
  float* b2p = (float*)((char*)d_ws + 1048576 + 32768 + 8192);   // 64 B

  nca_prep<<<81,   256, 0, stream>>>(W1, b1, W2, b2, w1fu, w2fu, b2p);
  nca_main<<<4096, 256, 0, stream>>>(x, im, w1fu, w2fu, b2p, out, bplane);
  nca_mask<<<4096, 256, 0, stream>>>(bplane, out);
}

// Round 15
// 90.087 us; speedup vs baseline: 2.3586x; 1.6920x over previous
//
#include <hip/hip_runtime.h>
#include <stdint.h>

#define C    14
#define CX   17      // C+3
#define PERC 51
#define HID  256

typedef __attribute__((ext_vector_type(4))) short  bf16x4;
typedef __attribute__((ext_vector_type(8))) short  bf16x8;
typedef __attribute__((ext_vector_type(4))) float  f32x4;
typedef __attribute__((ext_vector_type(8))) unsigned short u16x8;
typedef __attribute__((ext_vector_type(2))) uint32_t u32x2;

// ---------------- bf16 helpers ----------------
__device__ __forceinline__ float bfu(unsigned short u) {
  return __uint_as_float(((uint32_t)u) << 16);
}
__device__ __forceinline__ unsigned short bf16r(float f) {  // RNE (weights prep only)
  uint32_t u = __float_as_uint(f);
  return (unsigned short)((u + 0x7fffu + ((u >> 16) & 1u)) >> 16);
}
// Half-up pack (R8 known-good): round then take high 16 bits of each f32.
__device__ __forceinline__ uint32_t pack2_bf16(float lo, float hi) {
  const uint32_t ul = __float_as_uint(lo) + 0x8000u;
  const uint32_t uh = __float_as_uint(hi) + 0x8000u;
#if __has_builtin(__builtin_amdgcn_perm)
  return __builtin_amdgcn_perm(uh, ul, 0x07060302u);  // {uh[31:16], ul[31:16]}
#else
  return (uh & 0xffff0000u) | (ul >> 16);
#endif
}
__device__ __forceinline__ unsigned short pack1_bf16(float f) {
  return (unsigned short)((__float_as_uint(f) + 0x8000u) >> 16);
}

// ---------------- MFMA wrappers ----------------
__device__ __forceinline__ f32x4 mfma32(bf16x8 a, bf16x8 b, f32x4 c) {
  return __builtin_amdgcn_mfma_f32_16x16x32_bf16(a, b, c, 0, 0, 0);
}
#if __has_builtin(__builtin_amdgcn_mfma_f32_16x16x16bf16_1k)
#define HAVE_MFMA16_BUILTIN 1
#endif
__device__ __forceinline__ f32x4 mfma16(bf16x4 a, bf16x4 b, f32x4 c) {
#ifdef HAVE_MFMA16_BUILTIN
  return __builtin_amdgcn_mfma_f32_16x16x16bf16_1k(a, b, c, 0, 0, 0);
#else
  asm volatile("v_mfma_f32_16x16x16_bf16 %0, %1, %2, %0" : "+v"(c) : "v"(a), "v"(b));
  return c;
#endif
}

// ---------------- threefry2x32 (JAX partitionable) ----------------
__device__ __forceinline__ void tf_round(uint32_t& x0, uint32_t& x1, int r) {
  x0 += x1; x1 = (x1 << r) | (x1 >> (32 - r)); x1 ^= x0;
}
__device__ __forceinline__ void threefry2x32(uint32_t k0, uint32_t k1,
                                             uint32_t& x0, uint32_t& x1) {
  const uint32_t ks2 = k0 ^ k1 ^ 0x1BD11BDAu;
  x0 += k0; x1 += k1;
  tf_round(x0,x1,13); tf_round(x0,x1,15); tf_round(x0,x1,26); tf_round(x0,x1,6);
  x0 += k1; x1 += ks2 + 1u;
  tf_round(x0,x1,17); tf_round(x0,x1,29); tf_round(x0,x1,16); tf_round(x0,x1,24);
  x0 += ks2; x1 += k0 + 2u;
  tf_round(x0,x1,13); tf_round(x0,x1,15); tf_round(x0,x1,26); tf_round(x0,x1,6);
  x0 += k0; x1 += k1 + 3u;
  tf_round(x0,x1,17); tf_round(x0,x1,29); tf_round(x0,x1,16); tf_round(x0,x1,24);
  x0 += k1; x1 += ks2 + 4u;
  tf_round(x0,x1,13); tf_round(x0,x1,15); tf_round(x0,x1,26); tf_round(x0,x1,6);
  x0 += ks2; x1 += k0 + 5u;
}
__device__ __forceinline__ float upd_val(uint32_t gpix) {
  uint32_t fk0 = 0u, fk1 = 1234u;
  threefry2x32(0u, 0u, fk0, fk1);
  uint32_t a = 0u, b = gpix;
  threefry2x32(fk0, fk1, a, b);
  const uint32_t bits = a ^ b;
  const float u = __uint_as_float((bits >> 9) | 0x3f800000u) - 1.0f;
  return (u <= 0.5f) ? 1.0f : 0.0f;
}

// ---------------- kernel 0: weight fragment prep ----------------
__global__ void nca_prep(const float* __restrict__ W1, const float* __restrict__ b1,
                         const float* __restrict__ W2, const float* __restrict__ b2,
                         unsigned short* __restrict__ w1fu,
                         unsigned short* __restrict__ w2fu,
                         float* __restrict__ b2p) {
  const int bid = blockIdx.x, t = threadIdx.x;
  if (bid < 64) {
    const int f = bid * 256 + t;                 // 0..16383
    const int j = f & 7, l = (f >> 3) & 63, k2 = (f >> 9) & 1, mt = f >> 10;
    const int n = mt * 16 + (l & 15);
    const int k = k2 * 32 + ((l >> 4) & 3) * 8 + j;
    float v = 0.0f;
    if (k < PERC)       v = W1[k * HID + n];
    else if (k == PERC) v = b1[n];               // bias row
    w1fu[f] = bf16r(v);
  } else if (bid < 80) {
    const int f = (bid - 64) * 256 + t;          // 0..4095
    const int j = f & 3, l = (f >> 2) & 63, ks = f >> 8;
    const int co = l & 15;
    const int k = ks * 16 + ((l >> 4) & 3) * 4 + j;
    const float v = (co < C) ? W2[k * C + co] : 0.0f;
    w2fu[f] = bf16r(v);
  } else if (t < 16) {
    b2p[t] = (t < C) ? b2[t] : 0.0f;
  }
}

// ---------------- kernel 1: fused NCA step (16x16 pixel tile) ----------------
__global__ __launch_bounds__(256, 4)
void nca_main(const float* __restrict__ x, const float* __restrict__ img,
              const unsigned short* __restrict__ w1fu,
              const unsigned short* __restrict__ w2fu,
              const float* __restrict__ b2p,
              float* __restrict__ out, uint8_t* __restrict__ bplane) {
  // xcs and Ps have disjoint lifetimes separated by a barrier -> union
  // (33.8 KB LDS, 4 blocks/CU).
  __shared__ union {
    unsigned short xcs[18 * 18 * 24];  // bf16 halo tile, ch padded to 24 (31104 B)
    unsigned short Ps[256 * 64];       // perception, XOR-swizzled (32768 B)
  } sh;
  __shared__ float updf[256];

  const int t    = threadIdx.x;
  const int bid  = blockIdx.x;
  const int bb   = bid >> 8;
  const int tile = bid & 255;
  const int row0 = (tile >> 4) << 4, col0 = (tile & 15) << 4;

  // ---- stage xc halo (bf16, zero-padded borders) ----
  for (int e = t; e < 324; e += 256) {
    const int r = e / 18, c = e - r * 18;
    const int gr = row0 + r - 1, gc = col0 + c - 1;
    uint32_t w[8]; unsigned short w16;
    if ((unsigned)gr < 256u && (unsigned)gc < 256u) {
      const size_t gp = (size_t)bb * 65536 + (size_t)gr * 256 + gc;
      const float* xp = x + gp * C;
      float v[17];
      #pragma unroll
      for (int k = 0; k < 7; ++k) {
        const float2 f2 = *(const float2*)(xp + 2 * k);
        v[2 * k] = f2.x; v[2 * k + 1] = f2.y;
      }
      const float* ip = img + ((size_t)gr * 256 + gc) * 3;
      v[14] = ip[0]; v[15] = ip[1]; v[16] = ip[2];
      #pragma unroll
      for (int k = 0; k < 8; ++k)
        w[k] = pack2_bf16(v[2 * k], v[2 * k + 1]);
      w16 = pack1_bf16(v[16]);
    } else {
      #pragma unroll
      for (int k = 0; k < 8; ++k) w[k] = 0u;
      w16 = 0;
    }
    uint32_t* d = (uint32_t*)&sh.xcs[e * 24];
    #pragma unroll
    for (int k = 0; k < 8; ++k) d[k] = w[k];
    sh.xcs[e * 24 + 16] = w16;
  }

  // ---- stochastic update mask (one pixel per thread) ----
  {
    const uint32_t g = ((uint32_t)bb * 256u + (uint32_t)(row0 + (t >> 4))) * 256u
                       + (uint32_t)(col0 + (t & 15));
    updf[t] = upd_val(g);
  }
  __syncthreads();   // B1: xcs halo visible to all waves

  // ---- perception (pixel t) into registers ----
  const int pr = t >> 4, pc = t & 15;
  float pe[64];
  #pragma unroll
  for (int h = 0; h < 2; ++h) {
    u16x8 nb[9];
    #pragma unroll
    for (int i = 0; i < 3; ++i)
      #pragma unroll
      for (int j = 0; j < 3; ++j)
        nb[i * 3 + j] = *(const u16x8*)&sh.xcs[((pr + i) * 18 + (pc + j)) * 24 + h * 8];
    #pragma unroll
    for (int cc = 0; cc < 8; ++cc) {
      const int ch = h * 8 + cc;
      const float a00 = bfu(nb[0][cc]), a01 = bfu(nb[1][cc]), a02 = bfu(nb[2][cc]);
      const float a10 = bfu(nb[3][cc]), a11 = bfu(nb[4][cc]), a12 = bfu(nb[5][cc]);
      const float a20 = bfu(nb[6][cc]), a21 = bfu(nb[7][cc]), a22 = bfu(nb[8][cc]);
      pe[3 * ch + 0] = a11;
      pe[3 * ch + 1] = ((a02 - a00) + 2.0f * (a12 - a10) + (a22 - a20)) * 0.125f;
      pe[3 * ch + 2] = ((a20 - a00) + 2.0f * (a21 - a01) + (a22 - a02)) * 0.125f;
    }
  }
  {
    float a[9];
    #pragma unroll
    for (int i = 0; i < 3; ++i)
      #pragma unroll
      for (int j = 0; j < 3; ++j)
        a[i * 3 + j] = bfu(sh.xcs[((pr + i) * 18 + (pc + j)) * 24 + 16]);
    pe[48] = a[4];
    pe[49] = ((a[2] - a[0]) + 2.0f * (a[5] - a[3]) + (a[8] - a[6])) * 0.125f;
    pe[50] = ((a[6] - a[0]) + 2.0f * (a[7] - a[1]) + (a[8] - a[2])) * 0.125f;
  }
  pe[51] = 1.0f;                       // bias row (k=51 of W1 frags = b1)
  #pragma unroll
  for (int k = 52; k < 64; ++k) pe[k] = 0.0f;

  __syncthreads();   // B2: all xcs reads done before Ps overwrites union

  // ---- pack bf16, store swizzled to Ps ----
  #pragma unroll
  for (int g = 0; g < 8; ++g) {
    uint4 v;
    v.x = pack2_bf16(pe[g * 8 + 0], pe[g * 8 + 1]);
    v.y = pack2_bf16(pe[g * 8 + 2], pe[g * 8 + 3]);
    v.z = pack2_bf16(pe[g * 8 + 4], pe[g * 8 + 5]);
    v.w = pack2_bf16(pe[g * 8 + 6], pe[g * 8 + 7]);
    *(uint4*)&sh.Ps[(t << 6) + ((g ^ (t & 7)) << 3)] = v;
  }

  const int lane = t & 63;
  const int wv   = t >> 6;
  const int wbase = wv << 6;
  const int lg = lane >> 4;    // lane group (k-group / row-group)
  const int lc = lane & 15;    // pixel-within-16 (MFMA col)

  // Preload nc=0 A-fragments BEFORE the barrier (latency hides under the wait).
  bf16x8 aFc[4][2];
  #pragma unroll
  for (int m4 = 0; m4 < 4; ++m4)
    #pragma unroll
    for (int k2 = 0; k2 < 2; ++k2)
      aFc[m4][k2] = *(const bf16x8*)(w1fu + ((((m4 * 2 + k2) * 64) + lane) << 3));

  __syncthreads();   // B3: Ps cross-thread handoff (R4 lesson)

  // B-fragments: nc-invariant — load ONCE.
  bf16x8 bF0[4], bF1[4];
  #pragma unroll
  for (int nt = 0; nt < 4; ++nt) {
    const int pix = wbase + nt * 16 + lc;
    bF0[nt] = *(const bf16x8*)&sh.Ps[(pix << 6) + ((lg ^ (pix & 7)) << 3)];
    bF1[nt] = *(const bf16x8*)&sh.Ps[(pix << 6) + (((4 + lg) ^ (pix & 7)) << 3)];
  }

  f32x4 dxacc[4];
  {
    const float4 b2v = *(const float4*)(b2p + lg * 4);
    #pragma unroll
    for (int nt = 0; nt < 4; ++nt)
      dxacc[nt] = (f32x4){b2v.x, b2v.y, b2v.z, b2v.w};
  }

  __builtin_amdgcn_s_setprio(1);
  #pragma unroll
  for (int nc = 0; nc < 4; ++nc) {          // hidden 64-chunk
    if (nc > 0) {
      #pragma unroll
      for (int m4 = 0; m4 < 4; ++m4)
        #pragma unroll
        for (int k2 = 0; k2 < 2; ++k2)
          aFc[m4][k2] = *(const bf16x8*)(w1fu + (((((nc * 4 + m4) * 2 + k2) * 64) + lane) << 3));
    }

    f32x4 acc[4][4];
    #pragma unroll
    for (int m4 = 0; m4 < 4; ++m4)
      #pragma unroll
      for (int nt = 0; nt < 4; ++nt)
        acc[m4][nt] = (f32x4){0.0f, 0.0f, 0.0f, 0.0f};   // b1 folded into k=51

    #pragma unroll
    for (int nt = 0; nt < 4; ++nt) {
      #pragma unroll
      for (int m4 = 0; m4 < 4; ++m4) acc[m4][nt] = mfma32(aFc[m4][0], bF0[nt], acc[m4][nt]);
      #pragma unroll
      for (int m4 = 0; m4 < 4; ++m4) acc[m4][nt] = mfma32(aFc[m4][1], bF1[nt], acc[m4][nt]);
    }

    // GEMM2 partial: relu + half-up pack feeds the K=16 MFMA directly
    #pragma unroll
    for (int m4 = 0; m4 < 4; ++m4) {
      const bf16x4 wf = *(const bf16x4*)(w2fu + ((((nc * 4 + m4) * 64) + lane) << 2));
      #pragma unroll
      for (int nt = 0; nt < 4; ++nt) {
        u32x2 pw;
        pw.x = pack2_bf16(fmaxf(acc[m4][nt][0], 0.0f), fmaxf(acc[m4][nt][1], 0.0f));
        pw.y = pack2_bf16(fmaxf(acc[m4][nt][2], 0.0f), fmaxf(acc[m4][nt][3], 0.0f));
        dxacc[nt] = mfma16(wf, __builtin_bit_cast(bf16x4, pw), dxacc[nt]);
      }
    }
  }
  __builtin_amdgcn_s_setprio(0);
#ifndef HAVE_MFMA16_BUILTIN
  asm volatile("s_nop 7\n\ts_nop 7" :::);
#endif

  // ---- epilogue: x_new = x + 0.1 * dx * upd  (+ TILED alive-bit plane) ----
  // bplane layout: [bb][tile][pix] -> per wave the 4 nt stores cover 64
  // contiguous bytes (one full 64B line); per tile 256B = 4 exact lines.
  #pragma unroll
  for (int nt = 0; nt < 4; ++nt) {
    const int pix = wbase + nt * 16 + lc;
    const float sc = 0.1f * updf[pix];
    const int gr = row0 + (pix >> 4), gc = col0 + (pix & 15);
    const size_t gp = (size_t)bb * 65536 + (size_t)gr * 256 + gc;
    const float* xp = x + gp * C + lg * 4;
    float* op = out + gp * C + lg * 4;
    const f32x4 d = dxacc[nt];
    if (lg < 3) {
      const float2 u0 = *(const float2*)xp;
      const float2 u1 = *(const float2*)(xp + 2);
      const float r0 = u0.x + d[0] * sc, r1 = u0.y + d[1] * sc;
      const float r2 = u1.x + d[2] * sc, r3 = u1.y + d[3] * sc;
      *(float2*)op = make_float2(r0, r1);
      *(float2*)(op + 2) = make_float2(r2, r3);
      if (lg == 0) {
        // exact alive bits: bit0 = old ch0 > 0.1 (f32), bit1 = new ch0 > 0.1
        bplane[(size_t)bb * 65536 + (size_t)tile * 256 + pix] =
            (uint8_t)((u0.x > 0.1f ? 1 : 0) | (r0 > 0.1f ? 2 : 0));
      }
    } else {
      const float2 u0 = *(const float2*)xp;
      *(float2*)op = make_float2(u0.x + d[0] * sc, u0.y + d[1] * sc);
    }
  }
}

// ---------------- kernel 2: alive masking via tiled bit-plane ---------------
__global__ __launch_bounds__(256)
void nca_mask(const uint8_t* __restrict__ bp, float* __restrict__ out) {
  __shared__ uint8_t sb[18 * 18];
  const int t    = threadIdx.x;
  const int bid  = blockIdx.x;
  const int bb   = bid >> 8;
  const int tile = bid & 255;
  const int row0 = (tile >> 4) << 4, col0 = (tile & 15) << 4;

  for (int e = t; e < 324; e += 256) {
    const int r = e / 18, c = e - r * 18;
    const int gr = row0 + r - 1, gc = col0 + c - 1;
    uint8_t v = 0;   // border: pooled NEG_INF -> both tests false -> bits 0
    if ((unsigned)gr < 256u && (unsigned)gc < 256u) {
      const int tr = gr >> 4, tc = gc >> 4;          // tiled layout lookup
      v = bp[(size_t)bb * 65536 + (size_t)((tr << 4) + tc) * 256
             + ((gr & 15) << 4) + (gc & 15)];
    }
    sb[e] = v;
  }
  __syncthreads();

  const int pr = t >> 4, pc = t & 15;
  int m = 0;
  #pragma unroll
  for (int i = 0; i < 3; ++i)
    #pragma unroll
    for (int j = 0; j < 3; ++j)
      m |= sb[(pr + i) * 18 + pc + j];
  // alive = (pooled old > 0.1) && (pooled new > 0.1) = bit0 & bit1 of the OR
  if ((m & 3) != 3) {
    const size_t gp = ((size_t)bb * 256 + row0 + pr) * 256 + col0 + pc;
    float* __restrict__ o = out + gp * C;
    const float2 z = make_float2(0.0f, 0.0f);
    #pragma unroll
    for (int k = 0; k < 7; ++k) ((float2*)o)[k] = z;
  }
}

// ---------------- launch ----------------
extern "C" void kernel_launch(void* const* d_in, const int* in_sizes, int n_in,
                              void* d_out, int out_size, void* d_ws, size_t ws_size,
                              hipStream_t stream) {
  const float* x  = (const float*)d_in[0];
  const float* im = (const float*)d_in[1];
  const float* W1 = (const float*)d_in[2];
  const float* b1 = (const float*)d_in[3];
  const float* W2 = (const float*)d_in[4];
  const float* b2 = (const float*)d_in[5];
  float* out   = (float*)d_out;
  uint8_t* bplane = (uint8_t*)d_ws;                              // 1 MiB (tiled)
  unsigned short* w1fu = (unsigned short*)((char*)d_ws + 1048576);        // 32 KiB
  unsigned short* w2fu = (unsigned short*)((char*)d_ws + 1048576 + 32768); // 8 KiB
  float* b2p = (float*)((char*)d_ws + 1048576 + 32768 + 8192);   // 64 B

  nca_prep<<<81,   256, 0, stream>>>(W1, b1, W2, b2, w1fu, w2fu, b2p);
  nca_main<<<4096, 256, 0, stream>>>(x, im, w1fu, w2fu, b2p, out, bplane);
  nca_mask<<<4096, 256, 0, stream>>>(bplane, out);
}